// Round 14
// baseline (131.546 us; speedup 1.0000x reference)
//
#include <hip/hip_runtime.h>
#include <hip/hip_bf16.h>

typedef unsigned short u16;
typedef unsigned int u32;
typedef __attribute__((ext_vector_type(4))) float f32x4;
typedef __attribute__((ext_vector_type(16))) float f32x16;
typedef __attribute__((ext_vector_type(8))) short bf16x8;

__device__ inline u16 f2bf(float f) {
    union { float f; u32 u; } v; v.f = f;
    u32 r = v.u + 0x7fff + ((v.u >> 16) & 1);
    return (u16)(r >> 16);
}

__device__ inline f32x4 mfma16(bf16x8 a, bf16x8 b, f32x4 c) {
    return __builtin_amdgcn_mfma_f32_16x16x32_bf16(a, b, c, 0, 0, 0);
}
__device__ inline f32x16 mfma32(bf16x8 a, bf16x8 b, f32x16 c) {
    return __builtin_amdgcn_mfma_f32_32x32x16_bf16(a, b, c, 0, 0, 0);
}
__device__ inline u32 cvtpk(float lo, float hi) {
    u32 r;
    asm("v_cvt_pk_bf16_f32 %0, %1, %2" : "=v"(r) : "v"(lo), "v"(hi));
    return r;
}
__device__ inline float exp2v(float x) {
    float r;
    asm("v_exp_f32 %0, %1" : "=v"(r) : "v"(x));
    return r;
}

__device__ inline void gload_lds16(const void* g, const void* l) {
    __builtin_amdgcn_global_load_lds(
        (const __attribute__((address_space(1))) void*)g,
        (__attribute__((address_space(3))) void*)l, 16, 0, 0);
}

// log2(e) * head_dim^-0.5 — folded into q in the QKV epilogue (base-2 softmax)
#define QSCALE 0.18033688f

// ------- fused fp32 -> bf16 conversion (one pass) -------------------------
// x -> row-major bf16.  Weights -> FRAGMENT-ORDER:
//   Wf element (n,k): ((n>>7)*24 + (k>>5))*4096 + (n&127)*32 + (k&31)
// (8 KB per (col-tile, k-tile); GEMM B-fragment loads become contiguous
//  fully-utilized 1KB segments from L2-resident data, like R4's attn K/V.)
__global__ void cvt_all(const float* __restrict__ x,
                        const float* __restrict__ wq,
                        const float* __restrict__ wp,
                        u16* __restrict__ xb, u16* __restrict__ wqb,
                        u16* __restrict__ wpb) {
    int i = blockIdx.x * 256 + threadIdx.x;   // 0 .. 1081343
    const float* src; u16* dst; int off; bool frag;
    if (i < 786432)       { src = x;  dst = xb;  off = i;           frag = false; }
    else if (i < 1007616) { src = wq; dst = wqb; off = i - 786432;  frag = true;  }
    else                  { src = wp; dst = wpb; off = i - 1007616; frag = true;  }
    const float4* p = (const float4*)src;
    float4 a = p[2 * off], b = p[2 * off + 1];
    bf16x8 v;
    v[0] = (short)f2bf(a.x); v[1] = (short)f2bf(a.y);
    v[2] = (short)f2bf(a.z); v[3] = (short)f2bf(a.w);
    v[4] = (short)f2bf(b.x); v[5] = (short)f2bf(b.y);
    v[6] = (short)f2bf(b.z); v[7] = (short)f2bf(b.w);
    if (!frag) {
        ((bf16x8*)dst)[off] = v;
    } else {
        const int n = off / 96, k8 = off - n * 96;   // k = k8*8
        const int addr = (((n >> 7) * 24 + (k8 >> 2)) << 12) + ((n & 127) << 5) + ((k8 & 3) << 3);
        *(bf16x8*)&dst[addr] = v;
    }
}

// == GEMM 128x128, BK=32, 4 waves: A LDS-staged (2-buf counted-vmcnt), ====
// == B read directly from L2-resident FRAGMENT-ORDER global (no staging) ==
// C[M,N] = A[M,768] * B[N,768]^T. K=768 -> 24 tiles.
// Ledger (A-only, 2 gloads/tile): prologue 4 outstanding; in-loop vmcnt(2)
// drains exactly tile t; fb globals issued before stage(t+2) so compiler's
// pre-MFMA fb-drain (FIFO) leaves stage(t+2) in flight.
// EPI 0: Q row-major [bh][n][64]*QSCALE; K,V fragment-order (R4-proven).
// EPI 1: fp32 out [M][N] + bias
template <int EPI>
__global__ __launch_bounds__(256) void gemm_bL2(
    const u16* __restrict__ A, const u16* __restrict__ Bf,
    int nbn,                                  // N/128
    u16* __restrict__ qw, u16* __restrict__ kw, u16* __restrict__ vw,
    const float* __restrict__ qb, const float* __restrict__ vb,
    float* __restrict__ outp, const float* __restrict__ bproj)
{
    // 32 KB: pipeline uses [0..8192) u16 (2 x 8KB A buffers); epilogue all
    __shared__ __align__(16) u16 smem[16384];
    const int K = 768;
    const int NT = 24;
    const int tid = threadIdx.x;
    const int lane = tid & 63, wv = tid >> 6;
    const int nwg = gridDim.x;
    const int wg = (blockIdx.x & 7) * (nwg >> 3) + (blockIdx.x >> 3);
    const int bm = wg / nbn, bn = wg % nbn;
    const int row0 = bm << 7, col0 = bn << 7;

    // ---- A staging: 2 gloads/tile; row srow, swizzled source chunk sch ----
    const int srow = tid >> 2;                        // 0..63
    const int sch = (tid & 3) ^ ((srow >> 1) & 3);
    const u16* gA = A + (size_t)(row0 + srow) * K + sch * 8;
    const int ldst = wv * 512;                        // u16, wave-uniform

    auto stageA = [&](int bufi, int t) {
        u16* base = &smem[bufi * 4096];
        const int k0 = t << 5;
        gload_lds16(gA + k0,                   base + ldst);
        gload_lds16(gA + (size_t)64 * K + k0,  base + 2048 + ldst);
    };

    const int wr = (wv >> 1) << 6;   // wave row offset 0/64
    const int wc = (wv & 1) << 6;    // wave col offset 0/64
    const int arl = lane & 15, ahi = lane >> 4;
    bf16x8 fa[4], fb[4];
    auto loadFragsA = [&](int bufi) {
        const u16* bA = &smem[bufi * 4096];
#pragma unroll
        for (int fi = 0; fi < 4; ++fi) {
            const int rl = wr + fi * 16 + arl;
            fa[fi] = *(const bf16x8*)(bA + rl * 32 + ((ahi ^ ((rl >> 1) & 3)) << 3));
        }
    };
    // B fragments: contiguous 1KB per instruction, L2-resident
    const u16* gBlane = Bf + ((size_t)bn * NT << 12) + ((wc + arl) << 5) + (ahi << 3);
    auto loadFragsB = [&](int t) {
        const u16* bt = gBlane + (t << 12);
#pragma unroll
        for (int fj = 0; fj < 4; ++fj)
            fb[fj] = *(const bf16x8*)(bt + fj * 512);
    };

    f32x4 acc[4][4];
#pragma unroll
    for (int i = 0; i < 4; i++)
#pragma unroll
        for (int j = 0; j < 4; j++) acc[i][j] = (f32x4){0.f, 0.f, 0.f, 0.f};

    auto mfmaTile = [&]() {
        __builtin_amdgcn_s_setprio(1);
#pragma unroll
        for (int i = 0; i < 4; i++)
#pragma unroll
            for (int j = 0; j < 4; j++)
                acc[i][j] = mfma16(fa[i], fb[j], acc[i][j]);
        __builtin_amdgcn_s_setprio(0);
    };

    // ---- prologue: 2 A-tiles staged -> 4 loads in flight ----
    stageA(0, 0); stageA(1, 1);

    // ---- main loop, tiles 0..22 ----
#pragma unroll 1
    for (int t = 0; t < NT - 1; ++t) {
        asm volatile("s_waitcnt vmcnt(2)" ::: "memory");   // A tile t resident
        __builtin_amdgcn_s_barrier();
        loadFragsB(t);                                     // global (L2), oldest
        loadFragsA(t & 1);                                 // LDS
        asm volatile("s_waitcnt lgkmcnt(0)" ::: "memory");
        __builtin_amdgcn_sched_barrier(0);
        __builtin_amdgcn_s_barrier();                      // buffer t&1 free
        if (t < NT - 2) stageA(t & 1, t + 2);
        __builtin_amdgcn_sched_barrier(0);
        mfmaTile();                                        // compiler drains fb
    }
    // ---- tail: tile 23 (buf 1) ----
    asm volatile("s_waitcnt vmcnt(0)" ::: "memory");
    __builtin_amdgcn_s_barrier();
    loadFragsB(NT - 1);
    loadFragsA((NT - 1) & 1);
    asm volatile("s_waitcnt lgkmcnt(0)" ::: "memory");
    __builtin_amdgcn_sched_barrier(0);
    mfmaTile();
    __syncthreads();

    if (EPI == 0) {
        // ======= R5-proven epilogue: stage C-tile in smem (32 KB) =======
        const int part = col0 / 768;          // block-uniform: 0=Q 1=K 2=V
        const int colr0 = col0 - part * 768;  // multiple of 128
        const int h0 = colr0 >> 6;            // first of 2 heads in tile
        const int bb = row0 >> 10;            // batch
        const int n0 = row0 & 1023;           // multiple of 128

        if (part < 2) {
#pragma unroll
            for (int nj = 0; nj < 4; ++nj) {
                const int col = wc + nj * 16 + arl;
                const float bias = (part == 0) ? qb[colr0 + col] : 0.f;
                const float sc = (part == 0) ? QSCALE : 1.f;
#pragma unroll
                for (int mi = 0; mi < 4; ++mi) {
#pragma unroll
                    for (int j = 0; j < 4; ++j) {
                        const int row = wr + mi * 16 + (ahi << 2) + j;
                        smem[row * 128 + ((((col >> 3) ^ (row & 7)) << 3) | (col & 7))] =
                            f2bf((acc[mi][nj][j] + bias) * sc);
                    }
                }
            }
        } else {
#pragma unroll
            for (int nj = 0; nj < 4; ++nj) {
                const int col = wc + nj * 16 + arl;
                const float bias = vb[colr0 + col];
#pragma unroll
                for (int mi = 0; mi < 4; ++mi) {
                    const int row = wr + mi * 16 + (ahi << 2);  // row..row+3
                    ushort4 pk;
                    pk.x = f2bf(acc[mi][nj][0] + bias);
                    pk.y = f2bf(acc[mi][nj][1] + bias);
                    pk.z = f2bf(acc[mi][nj][2] + bias);
                    pk.w = f2bf(acc[mi][nj][3] + bias);
                    *(ushort4*)&smem[col * 128 +
                        ((((row >> 3) ^ (col & 7)) << 3) | (row & 7))] = pk;
                }
            }
        }
        __syncthreads();

        if (part == 0) {
#pragma unroll
            for (int p = 0; p < 8; ++p) {
                const int c = p * 256 + tid;
                const int h = c >> 10, ri = (c >> 3) & 127, j = c & 7;
                bf16x8 v = *(const bf16x8*)&smem[ri * 128 + ((((h << 3) + j) ^ (ri & 7)) << 3)];
                *(bf16x8*)&qw[((size_t)(((bb * 12 + h0 + h) << 10) + n0 + ri)) * 64 + j * 8] = v;
            }
        } else if (part == 1) {
#pragma unroll
            for (int p = 0; p < 8; ++p) {
                const int c = p * 256 + tid;
                const int h = c >> 10, t2 = (c >> 8) & 3, j = (c >> 5) & 7, r = c & 31;
                const int ri = t2 * 32 + r;
                bf16x8 v = *(const bf16x8*)&smem[ri * 128 + ((((h << 3) + j) ^ (ri & 7)) << 3)];
                *(bf16x8*)&kw[((size_t)(bb * 12 + h0 + h) << 16) +
                              (((n0 >> 5) + t2) << 11) + (j << 8) + (r << 3)] = v;
            }
        } else {
#pragma unroll
            for (int p = 0; p < 8; ++p) {
                const int c = p * 256 + tid;
                const int h = c >> 10, w = c & 1023;
                const int t2 = w >> 8, f = (w >> 6) & 3, ln = w & 63;
                const int d = ((f >> 1) << 5) + (ln & 31);
                const int rb_ = t2 * 32 + ((f & 1) << 4) + ((ln >> 5) << 3);
                const int ct = h * 64 + d;
                bf16x8 v = *(const bf16x8*)&smem[ct * 128 + (((rb_ >> 3) ^ (ct & 7)) << 3)];
                *(bf16x8*)&vw[((size_t)(bb * 12 + h0 + h) << 16) +
                              (((n0 >> 5) + t2) << 11) + (f << 9) + (ln << 3)] = v;
            }
        }
    } else {
        const int N = nbn << 7;
#pragma unroll
        for (int nj = 0; nj < 4; ++nj) {
            const int col = col0 + wc + nj * 16 + arl;
            const float bias = bproj[col];
#pragma unroll
            for (int mi = 0; mi < 4; ++mi) {
#pragma unroll
                for (int j = 0; j < 4; ++j) {
                    const int row = row0 + wr + mi * 16 + (ahi << 2) + j;
                    outp[(size_t)row * N + col] = acc[mi][nj][j] + bias;
                }
            }
        }
    }
}

// ---------------- flash attention, swapped-operand 32x32 MFMA ------------
__global__ __launch_bounds__(256, 3) void attn_fwd(
    const u16* __restrict__ Q, const u16* __restrict__ KF,
    const u16* __restrict__ VF, u16* __restrict__ O)
{
    __shared__ __align__(16) u16 tlds[4][32 * 68];
    const int tid = threadIdx.x, lane = tid & 63, wv = tid >> 6;
    const int l31 = lane & 31, hi = lane >> 5;
    const int bh = blockIdx.x % 96;
    const int qbk = blockIdx.x / 96;
    const int q0 = qbk * 128 + wv * 32;
    const size_t base = (size_t)bh << 16;
    const u16* Qp = Q + base;
    const u16* Kp = KF + base;
    const u16* Vp = VF + base;

    bf16x8 qf0, qf1, qf2, qf3;
    {
        const u16* qrow = &Qp[(q0 + l31) * 64 + hi * 8];
        qf0 = *(const bf16x8*)(qrow);
        qf1 = *(const bf16x8*)(qrow + 16);
        qf2 = *(const bf16x8*)(qrow + 32);
        qf3 = *(const bf16x8*)(qrow + 48);
    }

    f32x16 ot0, ot1;
#pragma unroll
    for (int i = 0; i < 16; ++i) { ot0[i] = 0.f; ot1[i] = 0.f; }
    float m = -1e30f, l = 0.f;

    auto loadK = [&](int t2048, bf16x8& f0, bf16x8& f1, bf16x8& f2, bf16x8& f3) {
        const u16* kr = &Kp[t2048 + hi * 256 + l31 * 8];
        f0 = *(const bf16x8*)(kr);
        f1 = *(const bf16x8*)(kr + 512);
        f2 = *(const bf16x8*)(kr + 1024);
        f3 = *(const bf16x8*)(kr + 1536);
    };

    auto body = [&](int t2048, bf16x8 k0, bf16x8 k1, bf16x8 k2, bf16x8 k3) {
        f32x16 s;
#pragma unroll
        for (int i = 0; i < 16; ++i) s[i] = 0.f;
        __builtin_amdgcn_s_setprio(1);
        s = mfma32(k0, qf0, s);
        s = mfma32(k1, qf1, s);
        s = mfma32(k2, qf2, s);
        s = mfma32(k3, qf3, s);
        __builtin_amdgcn_s_setprio(0);
        const u16* vrow = &Vp[t2048 + lane * 8];
        bf16x8 vf00 = *(const bf16x8*)(vrow);
        bf16x8 vf01 = *(const bf16x8*)(vrow + 512);
        bf16x8 vf10 = *(const bf16x8*)(vrow + 1024);
        bf16x8 vf11 = *(const bf16x8*)(vrow + 1536);
        float t0 = fmaxf(fmaxf(s[0], s[1]), fmaxf(s[2], s[3]));
        float t1 = fmaxf(fmaxf(s[4], s[5]), fmaxf(s[6], s[7]));
        float t2 = fmaxf(fmaxf(s[8], s[9]), fmaxf(s[10], s[11]));
        float t3 = fmaxf(fmaxf(s[12], s[13]), fmaxf(s[14], s[15]));
        float tmax = fmaxf(fmaxf(t0, t1), fmaxf(t2, t3));
        tmax = fmaxf(tmax, __shfl_xor(tmax, 32));
        if (!__all(tmax - m <= 8.f)) {
            const float nm = fmaxf(m, tmax);
            const float cr = exp2v(m - nm);
#pragma unroll
            for (int i = 0; i < 16; ++i) { ot0[i] *= cr; ot1[i] *= cr; }
            l *= cr; m = nm;
        }
#pragma unroll
        for (int i = 0; i < 16; ++i) { float p = exp2v(s[i] - m); s[i] = p; l += p; }
        u32 w0 = cvtpk(s[0],  s[1]),  w1 = cvtpk(s[2],  s[3]);
        u32 w2 = cvtpk(s[4],  s[5]),  w3 = cvtpk(s[6],  s[7]);
        u32 w4 = cvtpk(s[8],  s[9]),  w5 = cvtpk(s[10], s[11]);
        u32 w6 = cvtpk(s[12], s[13]), w7 = cvtpk(s[14], s[15]);
        asm("v_permlane32_swap_b32 %0, %1" : "+v"(w0), "+v"(w2));
        asm("v_permlane32_swap_b32 %0, %1" : "+v"(w1), "+v"(w3));
        asm("v_permlane32_swap_b32 %0, %1" : "+v"(w4), "+v"(w6));
        asm("v_permlane32_swap_b32 %0, %1" : "+v"(w5), "+v"(w7));
        union { u32 u[4]; bf16x8 v; } pb0, pb1;
        pb0.u[0] = w0; pb0.u[1] = w1; pb0.u[2] = w2; pb0.u[3] = w3;
        pb1.u[0] = w4; pb1.u[1] = w5; pb1.u[2] = w6; pb1.u[3] = w7;
        __builtin_amdgcn_s_setprio(1);
        ot0 = mfma32(vf00, pb0.v, ot0);
        ot0 = mfma32(vf01, pb1.v, ot0);
        ot1 = mfma32(vf10, pb0.v, ot1);
        ot1 = mfma32(vf11, pb1.v, ot1);
        __builtin_amdgcn_s_setprio(0);
    };

    bf16x8 ka0, ka1, ka2, ka3, kb0, kb1, kb2, kb3;
    loadK(0, ka0, ka1, ka2, ka3);
    for (int kt = 0; kt < 32; kt += 2) {
        loadK((kt + 1) << 11, kb0, kb1, kb2, kb3);
        body(kt << 11, ka0, ka1, ka2, ka3);
        if (kt + 2 < 32) loadK((kt + 2) << 11, ka0, ka1, ka2, ka3);
        body((kt + 1) << 11, kb0, kb1, kb2, kb3);
    }

    const float lt = l + __shfl_xor(l, 32);
    const float inv = 1.f / lt;
    u16* tw = &tlds[wv][0];
    u32* tw32 = (u32*)tw;
#pragma unroll
    for (int i = 0; i < 8; ++i) {
        const int dl = 2 * (i & 1) + 8 * (i >> 1) + 4 * hi;
        tw32[(l31 * 68 + dl) >> 1]      = cvtpk(ot0[2 * i] * inv, ot0[2 * i + 1] * inv);
        tw32[(l31 * 68 + dl + 32) >> 1] = cvtpk(ot1[2 * i] * inv, ot1[2 * i + 1] * inv);
    }
    __syncthreads();
    const int b = bh / 12, h = bh - b * 12;
    const size_t obase = ((size_t)(b << 10) + q0) * 768 + h * 64 + (lane & 7) * 8;
#pragma unroll
    for (int it = 0; it < 4; ++it) {
        const int r = it * 8 + (lane >> 3);
        bf16x8 v = *(const bf16x8*)&tw[r * 68 + (lane & 7) * 8];
        *(bf16x8*)&O[obase + (size_t)r * 768] = v;
    }
}

extern "C" void kernel_launch(void* const* d_in, const int* in_sizes, int n_in,
                              void* d_out, int out_size, void* d_ws, size_t ws_size,
                              hipStream_t stream) {
    const float* x      = (const float*)d_in[0];   // [8,1024,768]
    const float* w_qkv  = (const float*)d_in[1];   // [2304,768]
    const float* q_bias = (const float*)d_in[2];   // [768]
    const float* v_bias = (const float*)d_in[3];   // [768]
    const float* w_proj = (const float*)d_in[4];   // [768,768]
    const float* b_proj = (const float*)d_in[5];   // [768]
    float* out = (float*)d_out;                    // [8,1024,768] fp32

    char* ws = (char*)d_ws;
    u16* xb     = (u16*)(ws);                       // 12,582,912 B
    u16* wqkvb  = (u16*)(ws + 12582912);            //  3,538,944 B (fragment-order)
    u16* wprojb = (u16*)(ws + 16121856);            //  1,179,648 B (fragment-order)
    u16* qw     = (u16*)(ws + 17301504);            // 12,582,912 B
    u16* kw     = (u16*)(ws + 29884416);            // 12,582,912 B  (K fragment-order)
    u16* vt     = (u16*)(ws + 42467328);            // 12,582,912 B  (V fragment-order)
    u16* ob     = (u16*)(ws + 55050240);            // 12,582,912 B

    // one fused conversion pass: 1,081,344 chunks of 8 elems
    cvt_all<<<4224, 256, 0, stream>>>(x, w_qkv, w_proj, xb, wqkvb, wprojb);

    gemm_bL2<0><<<(8192 / 128) * (2304 / 128), 256, 0, stream>>>(
        xb, wqkvb, 2304 / 128, qw, kw, vt, q_bias, v_bias, nullptr, nullptr);

    attn_fwd<<<96 * 8, 256, 0, stream>>>(qw, kw, vt, ob);

    gemm_bL2<1><<<(8192 / 128) * (768 / 128), 256, 0, stream>>>(
        ob, wprojb, 768 / 128, nullptr, nullptr, nullptr, nullptr, nullptr, out, b_proj);
}

// Round 15
// 110.155 us; speedup vs baseline: 1.1942x; 1.1942x over previous
//
#include <hip/hip_runtime.h>
#include <hip/hip_bf16.h>

typedef unsigned short u16;
typedef unsigned int u32;
typedef __attribute__((ext_vector_type(4))) float f32x4;
typedef __attribute__((ext_vector_type(16))) float f32x16;
typedef __attribute__((ext_vector_type(8))) short bf16x8;

__device__ inline u16 f2bf(float f) {
    union { float f; u32 u; } v; v.f = f;
    u32 r = v.u + 0x7fff + ((v.u >> 16) & 1);
    return (u16)(r >> 16);
}

__device__ inline f32x4 mfma16(bf16x8 a, bf16x8 b, f32x4 c) {
    return __builtin_amdgcn_mfma_f32_16x16x32_bf16(a, b, c, 0, 0, 0);
}
__device__ inline f32x16 mfma32(bf16x8 a, bf16x8 b, f32x16 c) {
    return __builtin_amdgcn_mfma_f32_32x32x16_bf16(a, b, c, 0, 0, 0);
}
__device__ inline u32 cvtpk(float lo, float hi) {
    u32 r;
    asm("v_cvt_pk_bf16_f32 %0, %1, %2" : "=v"(r) : "v"(lo), "v"(hi));
    return r;
}
__device__ inline float exp2v(float x) {
    float r;
    asm("v_exp_f32 %0, %1" : "=v"(r) : "v"(x));
    return r;
}

__device__ inline void gload_lds16(const void* g, const void* l) {
    __builtin_amdgcn_global_load_lds(
        (const __attribute__((address_space(1))) void*)g,
        (__attribute__((address_space(3))) void*)l, 16, 0, 0);
}

// log2(e) * head_dim^-0.5 — folded into q in the QKV epilogue (base-2 softmax)
#define QSCALE 0.18033688f

// ------- fused fp32 -> bf16 conversion for x, w_qkv, w_proj (one pass) ----
// chunk i of 8 elems; ranges: x 786432 | w_qkv 221184 | w_proj 73728
__global__ void cvt_all(const float* __restrict__ x,
                        const float* __restrict__ wq,
                        const float* __restrict__ wp,
                        u16* __restrict__ xb, u16* __restrict__ wqb,
                        u16* __restrict__ wpb) {
    int i = blockIdx.x * 256 + threadIdx.x;   // 0 .. 1081343
    const float* src; u16* dst; int off;
    if (i < 786432)       { src = x;  dst = xb;  off = i; }
    else if (i < 1007616) { src = wq; dst = wqb; off = i - 786432; }
    else                  { src = wp; dst = wpb; off = i - 1007616; }
    const float4* p = (const float4*)src;
    float4 a = p[2 * off], b = p[2 * off + 1];
    bf16x8 v;
    v[0] = (short)f2bf(a.x); v[1] = (short)f2bf(a.y);
    v[2] = (short)f2bf(a.z); v[3] = (short)f2bf(a.w);
    v[4] = (short)f2bf(b.x); v[5] = (short)f2bf(b.y);
    v[6] = (short)f2bf(b.z); v[7] = (short)f2bf(b.w);
    ((bf16x8*)dst)[off] = v;
}

// ======= GEMM 128x128 tile, BK=32, 4 waves, 2-buffer counted-vmcnt =======
// (R10/R13-proven best: qkv 57.9 us, MfmaUtil ~19.5%.)
// C[M,N] = A[M,768] * B[N,768]^T. K=768 -> 24 tiles.
// Depth-2 pipeline: vmcnt(4) in-loop (never 0 until tail). 32 KB LDS ->
// 5 blocks/CU. R8 staging/read XOR swizzle, T1 XCD swizzle, T5 setprio.
// EPI 0: Q row-major [bh][n][64]*QSCALE; K,V fragment-order (R4-proven):
//   Kf: (n,d) -> (bh<<16) + (n>>5)*2048 + (d>>3)*256 + (n&31)*8 + (d&7)
//   Vf: (n,d) -> (bh<<16) + (n>>5)*2048 + ((d>>5)*2+((n&31)>>4))*512
//               + (((n>>3)&1)*32 + (d&31))*8 + (n&7)
// EPI 1: fp32 out [M][N] + bias
template <int EPI>
__global__ __launch_bounds__(256) void gemm_bt2(
    const u16* __restrict__ A, const u16* __restrict__ B,
    int nbn,                                  // N/128
    u16* __restrict__ qw, u16* __restrict__ kw, u16* __restrict__ vw,
    const float* __restrict__ qb, const float* __restrict__ vb,
    float* __restrict__ outp, const float* __restrict__ bproj)
{
    __shared__ __align__(16) u16 smem[16384];
    const int K = 768;
    const int NT = 24;
    const int tid = threadIdx.x;
    const int lane = tid & 63, wv = tid >> 6;
    const int nwg = gridDim.x;
    const int wg = (blockIdx.x & 7) * (nwg >> 3) + (blockIdx.x >> 3);
    const int bm = wg / nbn, bn = wg % nbn;
    const int row0 = bm << 7, col0 = bn << 7;

    const int srow = tid >> 2;                        // 0..63
    const int sch = (tid & 3) ^ ((srow >> 1) & 3);
    const u16* gA = A + (size_t)(row0 + srow) * K + sch * 8;
    const u16* gB = B + (size_t)(col0 + srow) * K + sch * 8;
    const int ldst = wv * 512;                        // u16, wave-uniform

    auto stageTile = [&](int bufi, int t) {
        u16* base = &smem[bufi * 8192];
        const int k0 = t << 5;
        gload_lds16(gA + k0,                   base + ldst);
        gload_lds16(gA + (size_t)64 * K + k0,  base + 2048 + ldst);
        gload_lds16(gB + k0,                   base + 4096 + ldst);
        gload_lds16(gB + (size_t)64 * K + k0,  base + 4096 + 2048 + ldst);
    };

    const int wr = (wv >> 1) << 6;   // wave row offset 0/64
    const int wc = (wv & 1) << 6;    // wave col offset 0/64
    const int arl = lane & 15, ahi = lane >> 4;
    bf16x8 fa[4], fb[4];
    auto loadFrags = [&](int bufi) {
        const u16* bA = &smem[bufi * 8192];
        const u16* bB = &smem[bufi * 8192 + 4096];
#pragma unroll
        for (int fi = 0; fi < 4; ++fi) {
            const int rl = wr + fi * 16 + arl;
            fa[fi] = *(const bf16x8*)(bA + rl * 32 + ((ahi ^ ((rl >> 1) & 3)) << 3));
        }
#pragma unroll
        for (int fj = 0; fj < 4; ++fj) {
            const int cl = wc + fj * 16 + arl;
            fb[fj] = *(const bf16x8*)(bB + cl * 32 + ((ahi ^ ((cl >> 1) & 3)) << 3));
        }
    };

    f32x4 acc[4][4];
#pragma unroll
    for (int i = 0; i < 4; i++)
#pragma unroll
        for (int j = 0; j < 4; j++) acc[i][j] = (f32x4){0.f, 0.f, 0.f, 0.f};

    auto mfmaTile = [&]() {
        __builtin_amdgcn_s_setprio(1);
#pragma unroll
        for (int i = 0; i < 4; i++)
#pragma unroll
            for (int j = 0; j < 4; j++)
                acc[i][j] = mfma16(fa[i], fb[j], acc[i][j]);
        __builtin_amdgcn_s_setprio(0);
    };

    // ---- prologue: 2 tiles staged -> 8 loads in flight ----
    stageTile(0, 0); stageTile(1, 1);

    // ---- main loop, tiles 0..22: loads stay 4-8 deep across barriers ----
#pragma unroll 1
    for (int t = 0; t < NT - 1; ++t) {
        asm volatile("s_waitcnt vmcnt(4)" ::: "memory");   // tile t resident
        __builtin_amdgcn_s_barrier();
        loadFrags(t & 1);
        asm volatile("s_waitcnt lgkmcnt(0)" ::: "memory");
        __builtin_amdgcn_sched_barrier(0);
        __builtin_amdgcn_s_barrier();                      // buffer t&1 free
        if (t < NT - 2) stageTile(t & 1, t + 2);
        __builtin_amdgcn_sched_barrier(0);
        mfmaTile();
    }
    // ---- tail: tile 23 (buf 1) ----
    asm volatile("s_waitcnt vmcnt(0)" ::: "memory");
    __builtin_amdgcn_s_barrier();
    loadFrags((NT - 1) & 1);
    asm volatile("s_waitcnt lgkmcnt(0)" ::: "memory");
    __builtin_amdgcn_sched_barrier(0);
    mfmaTile();
    __syncthreads();

    if (EPI == 0) {
        // ======= R5-proven epilogue: stage C-tile in smem (32 KB) =======
        const int part = col0 / 768;          // block-uniform: 0=Q 1=K 2=V
        const int colr0 = col0 - part * 768;  // multiple of 128
        const int h0 = colr0 >> 6;            // first of 2 heads in tile
        const int bb = row0 >> 10;            // batch
        const int n0 = row0 & 1023;           // multiple of 128

        if (part < 2) {
#pragma unroll
            for (int nj = 0; nj < 4; ++nj) {
                const int col = wc + nj * 16 + arl;
                const float bias = (part == 0) ? qb[colr0 + col] : 0.f;
                const float sc = (part == 0) ? QSCALE : 1.f;
#pragma unroll
                for (int mi = 0; mi < 4; ++mi) {
#pragma unroll
                    for (int j = 0; j < 4; ++j) {
                        const int row = wr + mi * 16 + (ahi << 2) + j;
                        smem[row * 128 + ((((col >> 3) ^ (row & 7)) << 3) | (col & 7))] =
                            f2bf((acc[mi][nj][j] + bias) * sc);
                    }
                }
            }
        } else {
#pragma unroll
            for (int nj = 0; nj < 4; ++nj) {
                const int col = wc + nj * 16 + arl;
                const float bias = vb[colr0 + col];
#pragma unroll
                for (int mi = 0; mi < 4; ++mi) {
                    const int row = wr + mi * 16 + (ahi << 2);  // row..row+3
                    ushort4 pk;
                    pk.x = f2bf(acc[mi][nj][0] + bias);
                    pk.y = f2bf(acc[mi][nj][1] + bias);
                    pk.z = f2bf(acc[mi][nj][2] + bias);
                    pk.w = f2bf(acc[mi][nj][3] + bias);
                    *(ushort4*)&smem[col * 128 +
                        ((((row >> 3) ^ (col & 7)) << 3) | (row & 7))] = pk;
                }
            }
        }
        __syncthreads();

        if (part == 0) {
#pragma unroll
            for (int p = 0; p < 8; ++p) {
                const int c = p * 256 + tid;
                const int h = c >> 10, ri = (c >> 3) & 127, j = c & 7;
                bf16x8 v = *(const bf16x8*)&smem[ri * 128 + ((((h << 3) + j) ^ (ri & 7)) << 3)];
                *(bf16x8*)&qw[((size_t)(((bb * 12 + h0 + h) << 10) + n0 + ri)) * 64 + j * 8] = v;
            }
        } else if (part == 1) {
#pragma unroll
            for (int p = 0; p < 8; ++p) {
                const int c = p * 256 + tid;
                const int h = c >> 10, t2 = (c >> 8) & 3, j = (c >> 5) & 7, r = c & 31;
                const int ri = t2 * 32 + r;
                bf16x8 v = *(const bf16x8*)&smem[ri * 128 + ((((h << 3) + j) ^ (ri & 7)) << 3)];
                *(bf16x8*)&kw[((size_t)(bb * 12 + h0 + h) << 16) +
                              (((n0 >> 5) + t2) << 11) + (j << 8) + (r << 3)] = v;
            }
        } else {
#pragma unroll
            for (int p = 0; p < 8; ++p) {
                const int c = p * 256 + tid;
                const int h = c >> 10, w = c & 1023;
                const int t2 = w >> 8, f = (w >> 6) & 3, ln = w & 63;
                const int d = ((f >> 1) << 5) + (ln & 31);
                const int rb_ = t2 * 32 + ((f & 1) << 4) + ((ln >> 5) << 3);
                const int ct = h * 64 + d;
                bf16x8 v = *(const bf16x8*)&smem[ct * 128 + (((rb_ >> 3) ^ (ct & 7)) << 3)];
                *(bf16x8*)&vw[((size_t)(bb * 12 + h0 + h) << 16) +
                              (((n0 >> 5) + t2) << 11) + (f << 9) + (ln << 3)] = v;
            }
        }
    } else {
        const int N = nbn << 7;
#pragma unroll
        for (int nj = 0; nj < 4; ++nj) {
            const int col = col0 + wc + nj * 16 + arl;
            const float bias = bproj[col];
#pragma unroll
            for (int mi = 0; mi < 4; ++mi) {
#pragma unroll
                for (int j = 0; j < 4; ++j) {
                    const int row = row0 + wr + mi * 16 + (ahi << 2) + j;
                    outp[(size_t)row * N + col] = acc[mi][nj][j] + bias;
                }
            }
        }
    }
}

// ---------------- flash attention, swapped-operand 32x32 MFMA ------------
__global__ __launch_bounds__(256, 3) void attn_fwd(
    const u16* __restrict__ Q, const u16* __restrict__ KF,
    const u16* __restrict__ VF, u16* __restrict__ O)
{
    __shared__ __align__(16) u16 tlds[4][32 * 68];
    const int tid = threadIdx.x, lane = tid & 63, wv = tid >> 6;
    const int l31 = lane & 31, hi = lane >> 5;
    const int bh = blockIdx.x % 96;
    const int qbk = blockIdx.x / 96;
    const int q0 = qbk * 128 + wv * 32;
    const size_t base = (size_t)bh << 16;
    const u16* Qp = Q + base;
    const u16* Kp = KF + base;
    const u16* Vp = VF + base;

    bf16x8 qf0, qf1, qf2, qf3;
    {
        const u16* qrow = &Qp[(q0 + l31) * 64 + hi * 8];
        qf0 = *(const bf16x8*)(qrow);
        qf1 = *(const bf16x8*)(qrow + 16);
        qf2 = *(const bf16x8*)(qrow + 32);
        qf3 = *(const bf16x8*)(qrow + 48);
    }

    f32x16 ot0, ot1;
#pragma unroll
    for (int i = 0; i < 16; ++i) { ot0[i] = 0.f; ot1[i] = 0.f; }
    float m = -1e30f, l = 0.f;

    auto loadK = [&](int t2048, bf16x8& f0, bf16x8& f1, bf16x8& f2, bf16x8& f3) {
        const u16* kr = &Kp[t2048 + hi * 256 + l31 * 8];
        f0 = *(const bf16x8*)(kr);
        f1 = *(const bf16x8*)(kr + 512);
        f2 = *(const bf16x8*)(kr + 1024);
        f3 = *(const bf16x8*)(kr + 1536);
    };

    auto body = [&](int t2048, bf16x8 k0, bf16x8 k1, bf16x8 k2, bf16x8 k3) {
        f32x16 s;
#pragma unroll
        for (int i = 0; i < 16; ++i) s[i] = 0.f;
        __builtin_amdgcn_s_setprio(1);
        s = mfma32(k0, qf0, s);
        s = mfma32(k1, qf1, s);
        s = mfma32(k2, qf2, s);
        s = mfma32(k3, qf3, s);
        __builtin_amdgcn_s_setprio(0);
        const u16* vrow = &Vp[t2048 + lane * 8];
        bf16x8 vf00 = *(const bf16x8*)(vrow);
        bf16x8 vf01 = *(const bf16x8*)(vrow + 512);
        bf16x8 vf10 = *(const bf16x8*)(vrow + 1024);
        bf16x8 vf11 = *(const bf16x8*)(vrow + 1536);
        float t0 = fmaxf(fmaxf(s[0], s[1]), fmaxf(s[2], s[3]));
        float t1 = fmaxf(fmaxf(s[4], s[5]), fmaxf(s[6], s[7]));
        float t2 = fmaxf(fmaxf(s[8], s[9]), fmaxf(s[10], s[11]));
        float t3 = fmaxf(fmaxf(s[12], s[13]), fmaxf(s[14], s[15]));
        float tmax = fmaxf(fmaxf(t0, t1), fmaxf(t2, t3));
        tmax = fmaxf(tmax, __shfl_xor(tmax, 32));
        if (!__all(tmax - m <= 8.f)) {
            const float nm = fmaxf(m, tmax);
            const float cr = exp2v(m - nm);
#pragma unroll
            for (int i = 0; i < 16; ++i) { ot0[i] *= cr; ot1[i] *= cr; }
            l *= cr; m = nm;
        }
#pragma unroll
        for (int i = 0; i < 16; ++i) { float p = exp2v(s[i] - m); s[i] = p; l += p; }
        u32 w0 = cvtpk(s[0],  s[1]),  w1 = cvtpk(s[2],  s[3]);
        u32 w2 = cvtpk(s[4],  s[5]),  w3 = cvtpk(s[6],  s[7]);
        u32 w4 = cvtpk(s[8],  s[9]),  w5 = cvtpk(s[10], s[11]);
        u32 w6 = cvtpk(s[12], s[13]), w7 = cvtpk(s[14], s[15]);
        asm("v_permlane32_swap_b32 %0, %1" : "+v"(w0), "+v"(w2));
        asm("v_permlane32_swap_b32 %0, %1" : "+v"(w1), "+v"(w3));
        asm("v_permlane32_swap_b32 %0, %1" : "+v"(w4), "+v"(w6));
        asm("v_permlane32_swap_b32 %0, %1" : "+v"(w5), "+v"(w7));
        union { u32 u[4]; bf16x8 v; } pb0, pb1;
        pb0.u[0] = w0; pb0.u[1] = w1; pb0.u[2] = w2; pb0.u[3] = w3;
        pb1.u[0] = w4; pb1.u[1] = w5; pb1.u[2] = w6; pb1.u[3] = w7;
        __builtin_amdgcn_s_setprio(1);
        ot0 = mfma32(vf00, pb0.v, ot0);
        ot0 = mfma32(vf01, pb1.v, ot0);
        ot1 = mfma32(vf10, pb0.v, ot1);
        ot1 = mfma32(vf11, pb1.v, ot1);
        __builtin_amdgcn_s_setprio(0);
    };

    bf16x8 ka0, ka1, ka2, ka3, kb0, kb1, kb2, kb3;
    loadK(0, ka0, ka1, ka2, ka3);
    for (int kt = 0; kt < 32; kt += 2) {
        loadK((kt + 1) << 11, kb0, kb1, kb2, kb3);
        body(kt << 11, ka0, ka1, ka2, ka3);
        if (kt + 2 < 32) loadK((kt + 2) << 11, ka0, ka1, ka2, ka3);
        body((kt + 1) << 11, kb0, kb1, kb2, kb3);
    }

    const float lt = l + __shfl_xor(l, 32);
    const float inv = 1.f / lt;
    u16* tw = &tlds[wv][0];
    u32* tw32 = (u32*)tw;
#pragma unroll
    for (int i = 0; i < 8; ++i) {
        const int dl = 2 * (i & 1) + 8 * (i >> 1) + 4 * hi;
        tw32[(l31 * 68 + dl) >> 1]      = cvtpk(ot0[2 * i] * inv, ot0[2 * i + 1] * inv);
        tw32[(l31 * 68 + dl + 32) >> 1] = cvtpk(ot1[2 * i] * inv, ot1[2 * i + 1] * inv);
    }
    __syncthreads();
    const int b = bh / 12, h = bh - b * 12;
    const size_t obase = ((size_t)(b << 10) + q0) * 768 + h * 64 + (lane & 7) * 8;
#pragma unroll
    for (int it = 0; it < 4; ++it) {
        const int r = it * 8 + (lane >> 3);
        bf16x8 v = *(const bf16x8*)&tw[r * 68 + (lane & 7) * 8];
        *(bf16x8*)&O[obase + (size_t)r * 768] = v;
    }
}

extern "C" void kernel_launch(void* const* d_in, const int* in_sizes, int n_in,
                              void* d_out, int out_size, void* d_ws, size_t ws_size,
                              hipStream_t stream) {
    const float* x      = (const float*)d_in[0];   // [8,1024,768]
    const float* w_qkv  = (const float*)d_in[1];   // [2304,768]
    const float* q_bias = (const float*)d_in[2];   // [768]
    const float* v_bias = (const float*)d_in[3];   // [768]
    const float* w_proj = (const float*)d_in[4];   // [768,768]
    const float* b_proj = (const float*)d_in[5];   // [768]
    float* out = (float*)d_out;                    // [8,1024,768] fp32

    char* ws = (char*)d_ws;
    u16* xb     = (u16*)(ws);                       // 12,582,912 B
    u16* wqkvb  = (u16*)(ws + 12582912);            //  3,538,944 B
    u16* wprojb = (u16*)(ws + 16121856);            //  1,179,648 B
    u16* qw     = (u16*)(ws + 17301504);            // 12,582,912 B
    u16* kw     = (u16*)(ws + 29884416);            // 12,582,912 B  (K fragment-order)
    u16* vt     = (u16*)(ws + 42467328);            // 12,582,912 B  (V fragment-order)
    u16* ob     = (u16*)(ws + 55050240);            // 12,582,912 B

    // one fused conversion pass: 1,081,344 chunks of 8 elems
    cvt_all<<<4224, 256, 0, stream>>>(x, w_qkv, w_proj, xb, wqkvb, wprojb);

    gemm_bt2<0><<<(8192 / 128) * (2304 / 128), 256, 0, stream>>>(
        xb, wqkvb, 2304 / 128, qw, kw, vt, q_bias, v_bias, nullptr, nullptr);

    attn_fwd<<<96 * 8, 256, 0, stream>>>(qw, kw, vt, ob);

    gemm_bt2<1><<<(8192 / 128) * (768 / 128), 256, 0, stream>>>(
        ob, wprojb, 768 / 128, nullptr, nullptr, nullptr, nullptr, nullptr, out, b_proj);
}